// Round 1
// baseline (161.535 us; speedup 1.0000x reference)
//
#include <hip/hip_runtime.h>

// B=8, N=256, D=128, 2D=256.
// out = tour [8,256] (arange) ++ improvement_matrix [8,256,256].

typedef __attribute__((ext_vector_type(8))) short short8;
typedef __attribute__((ext_vector_type(8))) _Float16 half8;
typedef __attribute__((ext_vector_type(4))) float floatx4;

static __device__ __forceinline__ unsigned short f2bf(float f) {
  unsigned int x = __float_as_uint(f);
  x += 0x7fff + ((x >> 16) & 1);   // RNE fp32 -> bf16
  return (unsigned short)(x >> 16);
}

static __device__ __forceinline__ unsigned short f2h(float f) {
  _Float16 h = (_Float16)f;        // RNE fp32 -> fp16
  return __builtin_bit_cast(unsigned short, h);
}

static __device__ __forceinline__ float fast_tanh(float x) {
  float e = __expf(2.0f * fabsf(x));                       // e^{2|x|}
  float t = 1.0f - 2.0f * __builtin_amdgcn_rcpf(e + 1.0f); // in [0,1)
  return copysignf(t, x);
}

// pack 8 fp16 -> 8 OCP e4m3 bytes (via f32, v_cvt_pk_fp8_f32)
static __device__ __forceinline__ long pack_fp8(half8 s) {
  int lo = __builtin_amdgcn_cvt_pk_fp8_f32((float)s[0], (float)s[1], 0, false);
  lo = __builtin_amdgcn_cvt_pk_fp8_f32((float)s[2], (float)s[3], lo, true);
  int hi = __builtin_amdgcn_cvt_pk_fp8_f32((float)s[4], (float)s[5], 0, false);
  hi = __builtin_amdgcn_cvt_pk_fp8_f32((float)s[6], (float)s[7], hi, true);
  return (long)(unsigned)lo | ((long)hi << 32);
}

// async global->LDS DMA, 16B per lane. LDS dest = wave-uniform base + lane*16
// (m104); global src is per-lane. Swizzled layouts are achieved by
// PRE-SWIZZLING the global buffer in k_prep (m173 pattern), dest stays linear.
static __device__ __forceinline__ void gload_lds16(const void* g, void* l) {
  __builtin_amdgcn_global_load_lds(
      (const __attribute__((address_space(1))) unsigned int*)g,
      (__attribute__((address_space(3))) unsigned int*)l, 16, 0, 0);
}

// ---- k_prep: tour | zero matrix | W2->fp8(x16) | W1->bf16 T | xcat bf16 ----
// W2F8 / W1T / xcat are written in the LDS-swizzled order their consumers
// want, so k_proj/k_main can stage them with linear global_load_lds.
__global__ __launch_bounds__(256) void k_prep(
    const float* __restrict__ x, const float* __restrict__ W1,
    const float* __restrict__ W2, float* __restrict__ out,
    unsigned char* __restrict__ W2F8, unsigned short* __restrict__ W1T,
    unsigned short* __restrict__ xcat) {
  int e = blockIdx.x * 256 + threadIdx.x;   // grid covers 1198080
  if (e < 2048) {
    out[e] = (float)(e & 255);              // improved_tour rows = arange
  } else if (e < 526336) {
    out[e] = 0.f;                           // zero matrix (uncovered tiles)
  } else if (e < 542720) {
    int t = e - 526336;                     // 16384 k-pairs of W2
    int p = t >> 7, n = t & 127;            // p = k/2, n = out channel
    float f0 = W2[(2 * p) * 128 + n] * 16.f;       // x16: into e4m3 normal range
    float f1 = W2[(2 * p + 1) * 128 + n] * 16.f;
    int v2 = __builtin_amdgcn_cvt_pk_fp8_f32(f0, f1, 0, false);
    // swizzled byte col: chunk v=(2p)>>4 xored with row&15, offset (2p)&15
    int col = 2 * p;
    int sw = (((col >> 4) ^ (n & 15)) << 4) | (col & 15);
    *(unsigned short*)(W2F8 + n * 256 + sw) = (unsigned short)(v2 & 0xffff);
  } else if (e < 673792) {
    int e3 = e - 542720;                    // 131072: W1T [512 n][256 k]
    int n = e3 >> 8, k = e3 & 255;
    int v = k >> 3;                         // 8-ushort (16B) chunk id 0..31
    int sw = (((v & 16) | ((v ^ (n & 15)) & 15)) << 3) | (k & 7);
    W1T[(n << 8) + sw] = f2bf(W1[((k + (n & 256)) << 8) + (n & 255)]);
  } else {
    int e4 = e - 673792;                    // 524288: xcat [2048 r][256 k]
    int r = e4 >> 8, k = e4 & 255;
    int v = k >> 3;
    int sw = (((v & 16) | ((v ^ (r & 15)) & 15)) << 3) | (k & 7);
    int pos = r & 255;
    int pos2 = (k < 128) ? pos : ((pos + 1) & 255);
    xcat[(r << 8) + sw] = f2bf(x[(((r >> 8) << 8) + pos2) * 128 + (k & 127)]);
  }
}

// ---- k_proj: MFMA GEMM  [2048 rows x 256 K] @ [K x 512 ch] -> PiH | PjH ----
// Staging now via global_load_lds (linear dest; sources pre-swizzled by
// k_prep). LDS contents are bit-identical to the old register-staged version,
// so the fragment-read side is unchanged.
__global__ __launch_bounds__(256) void k_proj(
    const unsigned short* __restrict__ xcat, const unsigned short* __restrict__ W1T,
    const float* __restrict__ b1, unsigned short* __restrict__ PiH,
    unsigned short* __restrict__ PjH) {
  const int mg = blockIdx.x >> 3;       // 0..31 row-tile
  const int ng = blockIdx.x & 7;        // 0..7 channel-tile
  const int tid = threadIdx.x;
  const int wr = tid >> 6, lane = tid & 63, quad = lane >> 4, l15 = lane & 15;

  __shared__ unsigned short As[64 * 256];   // 32KB rows tile (swizzled)
  __shared__ unsigned short Bs[64 * 256];   // 32KB W1T tile (swizzled)

  const unsigned short* Asrc = xcat + mg * 64 * 256;
  const unsigned short* Bsrc = W1T + ng * 64 * 256;
#pragma unroll
  for (int it = 0; it < 8; ++it) {
    const int c = it * 256 + wr * 64 + lane;     // 16B chunk id 0..2047
    gload_lds16(Asrc + c * 8, &As[(it * 256 + wr * 64) * 8]);
    gload_lds16(Bsrc + c * 8, &Bs[(it * 256 + wr * 64) * 8]);
  }
  __syncthreads();   // drains the DMA (compiler emits vmcnt(0) before barrier)

  floatx4 acc[4];
#pragma unroll
  for (int mt = 0; mt < 4; ++mt) acc[mt] = (floatx4)0.f;

  const char* Ab = (const char*)As;
  const char* Bb = (const char*)Bs + wr * 16 * 512;
  const int base_sw = l15 * 512 + ((quad ^ l15) << 4);

#pragma unroll
  for (int ks = 0; ks < 8; ++ks) {
    const int swz = base_sw ^ (ks << 6);
    short8 bfr = *(const short8*)(Bb + swz);
#pragma unroll
    for (int mt = 0; mt < 4; ++mt) {
      short8 afr = *(const short8*)(Ab + mt * 8192 + swz);
      acc[mt] = __builtin_amdgcn_mfma_f32_16x16x32_bf16(afr, bfr, acc[mt], 0, 0, 0);
    }
  }

  const int ch = ng * 64 + wr * 16 + l15;          // 0..511 (wave-uniform side)
  const float bias = (ch < 256) ? b1[ch] : 0.f;
  unsigned short* dst = (ch < 256) ? PiH : PjH;
  const int chan = ch & 255;
#pragma unroll
  for (int mt = 0; mt < 4; ++mt)
#pragma unroll
    for (int r = 0; r < 4; ++r) {
      int row = mg * 64 + mt * 16 + quad * 4 + r;  // global row b*256+pos
      dst[row * 256 + chan] = f2h(acc[mt][r] + bias);
    }
}

// ---- k_main: persistent-grid packed items + fp8 pair-GEMM. -----------------
// 9088 items (1136/b x 8b). Grid = 1024 blocks x 256 thr (exactly 4 blocks/CU
// at __launch_bounds__(256,4): 128KB LDS/CU, 16 waves/CU vs 12 before — the
// occupancy lever for the latency-bound per-ks chain). Each wave strides
// items e2, e2+4096, e2+8192: W2 staged 1024x (was 2272x), no partial round.
// B-frag ds_reads split 2x4 (-8 VGPR to fit the 128-reg cap); MFMA bursts
// wrapped in s_setprio(1) (T5: waves are independent items -> role diversity).
__global__ __launch_bounds__(256, 4) void k_main(
    const unsigned short* __restrict__ PiH, const unsigned short* __restrict__ PjH,
    const unsigned char* __restrict__ W2F8, const float* __restrict__ b2,
    const float* __restrict__ W3, const float* __restrict__ b3,
    float* __restrict__ outm) {
  const int tid = threadIdx.x;
  const int wr = tid >> 6;              // wave 0..3
  const int lane = tid & 63, quad = lane >> 4, l15 = lane & 15;

  __shared__ unsigned char W2s[128 * 256];   // 32KB fp8, [n][k'] swizzled

  // stage 32KB via DMA: 2048 16B chunks, linear dest (source pre-swizzled)
#pragma unroll
  for (int it = 0; it < 8; ++it) {
    const int c = it * 256 + wr * 64 + lane;
    gload_lds16(W2F8 + c * 16, &W2s[(it * 256 + wr * 64) * 16]);
  }
  __syncthreads();

  const char* W2base = (const char*)&W2s[0];
  const int base_sw = l15 * 256 + ((((quad >> 1) ^ l15) & 15) << 4) + ((quad & 1) << 3);
  const float b3v = b3[0];
  const float s16 = 0.0625f;               // undo W2 x16 scale

#pragma unroll 1
  for (int e2 = blockIdx.x * 4 + wr; e2 < 9088; e2 += 4096) {
    // decode packed item e2 -> (b, jt, i)   [wave-uniform]
    const int b = (int)(((unsigned)e2 * 14769u) >> 24);   // e2 / 1136
    const int e = e2 - b * 1136;
    int jt = 0, base = 0;
    if (e >= 30)  { jt = 1; base = 30;  }
    if (e >= 92)  { jt = 2; base = 92;  }
    if (e >= 186) { jt = 3; base = 186; }
    if (e >= 312) { jt = 4; base = 312; }
    if (e >= 470) { jt = 5; base = 470; }
    if (e >= 660) { jt = 6; base = 660; }
    if (e >= 882) { jt = 7; base = 882; }
    const int i = e - base;                    // 0 .. jt*32+29

    const unsigned short* Pjb = PjH + ((b << 8) + jt * 32 + l15) * 256 + quad * 8;
    const unsigned short* PiRow = PiH + ((b << 8) + i) * 256 + quad * 8;

    floatx4 acc[2][8];
#pragma unroll
    for (int mt = 0; mt < 2; ++mt)
#pragma unroll
      for (int nt = 0; nt < 8; ++nt) acc[mt][nt] = (floatx4)0.f;

    union U4 { uint4 v; half8 h; };
    U4 piR[2], pjR[2][2];
    piR[0].v = *(const uint4*)(PiRow);
    pjR[0][0].v = *(const uint4*)(Pjb);
    pjR[0][1].v = *(const uint4*)(Pjb + 4096);   // mt=1: +16 rows

#pragma unroll
    for (int ks = 0; ks < 8; ++ks) {
      const int cur = ks & 1, nxt = cur ^ 1;
      // (1) depth-1 global prefetch for ks+1 (longest latency — issue first)
      if (ks < 7) {
        piR[nxt].v = *(const uint4*)(PiRow + (ks + 1) * 32);
        pjR[nxt][0].v = *(const uint4*)(Pjb + (ks + 1) * 32);
        pjR[nxt][1].v = *(const uint4*)(Pjb + 4096 + (ks + 1) * 32);
      }
      // (2) first half of this iteration's B-frag LDS reads
      const char* baddr = W2base + (base_sw ^ (ks << 5));
      long bfr0[4];
#pragma unroll
      for (int nt = 0; nt < 4; ++nt) bfr0[nt] = *(const long*)(baddr + nt * 4096);
      // (3) build A-frags: packed fp16 relu(Pi+Pj), then pack to e4m3
      const half8 s0 = __builtin_elementwise_max(piR[cur].h + pjR[cur][0].h,
                                                 (half8)(_Float16)0);
      const half8 s1 = __builtin_elementwise_max(piR[cur].h + pjR[cur][1].h,
                                                 (half8)(_Float16)0);
      const long a0 = pack_fp8(s0);
      const long a1 = pack_fp8(s1);
      // (4) MFMA burst 1 (covers batch-2 ds latency)
      __builtin_amdgcn_s_setprio(1);
#pragma unroll
      for (int nt = 0; nt < 4; ++nt) {
        acc[0][nt] = __builtin_amdgcn_mfma_f32_16x16x32_fp8_fp8(a0, bfr0[nt], acc[0][nt], 0, 0, 0);
        acc[1][nt] = __builtin_amdgcn_mfma_f32_16x16x32_fp8_fp8(a1, bfr0[nt], acc[1][nt], 0, 0, 0);
      }
      __builtin_amdgcn_s_setprio(0);
      // (5) second half of B-frags + burst 2
      long bfr1[4];
#pragma unroll
      for (int nt = 0; nt < 4; ++nt) bfr1[nt] = *(const long*)(baddr + (nt + 4) * 4096);
      __builtin_amdgcn_s_setprio(1);
#pragma unroll
      for (int nt = 0; nt < 4; ++nt) {
        acc[0][nt + 4] = __builtin_amdgcn_mfma_f32_16x16x32_fp8_fp8(a0, bfr1[nt], acc[0][nt + 4], 0, 0, 0);
        acc[1][nt + 4] = __builtin_amdgcn_mfma_f32_16x16x32_fp8_fp8(a1, bfr1[nt], acc[1][nt + 4], 0, 0, 0);
      }
      __builtin_amdgcn_s_setprio(0);
    }

    // epilogue: score[j] = tanh(sum_n W3[n]*relu(C[j,n]/16 + b2[n]) + b3)
    float* orow = outm + ((b << 8) + i) * 256 + jt * 32;
#pragma unroll
    for (int mt = 0; mt < 2; ++mt) {
      float p0 = 0, p1 = 0, p2 = 0, p3 = 0;
#pragma unroll
      for (int nt = 0; nt < 8; ++nt) {
        float w3v = W3[nt * 16 + l15];
        float b2v = b2[nt * 16 + l15];
        floatx4 a = acc[mt][nt];
        p0 += fmaxf(fmaf(a[0], s16, b2v), 0.f) * w3v;
        p1 += fmaxf(fmaf(a[1], s16, b2v), 0.f) * w3v;
        p2 += fmaxf(fmaf(a[2], s16, b2v), 0.f) * w3v;
        p3 += fmaxf(fmaf(a[3], s16, b2v), 0.f) * w3v;
      }
#pragma unroll
      for (int m = 8; m >= 1; m >>= 1) {   // reduce over the 16 n-cols per quad
        p0 += __shfl_xor(p0, m, 16);
        p1 += __shfl_xor(p1, m, 16);
        p2 += __shfl_xor(p2, m, 16);
        p3 += __shfl_xor(p3, m, 16);
      }
      if (l15 == 0) {
        const int jl = jt * 32 + mt * 16 + quad * 4;   // global j of reg 0
        float ps[4] = {p0, p1, p2, p3};
#pragma unroll
        for (int r = 0; r < 4; ++r) {
          int j = jl + r;
          float sc = fast_tanh(ps[r] + b3v);
          bool valid = (j >= i + 2) && (j - i != 255);
          orow[mt * 16 + quad * 4 + r] = valid ? sc : 0.f;
        }
      }
    }
  }
}

extern "C" void kernel_launch(void* const* d_in, const int* in_sizes, int n_in,
                              void* d_out, int out_size, void* d_ws, size_t ws_size,
                              hipStream_t stream) {
  const float* x  = (const float*)d_in[0];   // [8,256,128]
  const float* W1 = (const float*)d_in[1];   // [512,256]
  const float* b1 = (const float*)d_in[2];   // [256]
  const float* W2 = (const float*)d_in[3];   // [256,128]
  const float* b2 = (const float*)d_in[4];   // [128]
  const float* W3 = (const float*)d_in[5];   // [128]
  const float* b3 = (const float*)d_in[6];   // [1]
  float* out = (float*)d_out;

  // ws (ushort units): PiH 524288 | PjH 524288 | W1T 131072 | xcat 524288 | W2F8 32KB
  unsigned short* PiH  = (unsigned short*)d_ws;
  unsigned short* PjH  = PiH + 524288;
  unsigned short* W1T  = PjH + 524288;
  unsigned short* xcat = W1T + 131072;
  unsigned char*  W2F8 = (unsigned char*)(xcat + 524288);

  k_prep<<<4680, 256, 0, stream>>>(x, W1, W2, out, W2F8, W1T, xcat);
  k_proj<<<256, 256, 0, stream>>>(xcat, W1T, b1, PiH, PjH);
  k_main<<<1024, 256, 0, stream>>>(PiH, PjH, W2F8, b2, W3, b3, out + 2048);
}

// Round 2
// 150.683 us; speedup vs baseline: 1.0720x; 1.0720x over previous
//
#include <hip/hip_runtime.h>

// B=8, N=256, D=128, 2D=256.
// out = tour [8,256] (arange) ++ improvement_matrix [8,256,256].

typedef __attribute__((ext_vector_type(8))) short short8;
typedef __attribute__((ext_vector_type(8))) _Float16 half8;
typedef __attribute__((ext_vector_type(4))) float floatx4;

static __device__ __forceinline__ unsigned short f2bf(float f) {
  unsigned int x = __float_as_uint(f);
  x += 0x7fff + ((x >> 16) & 1);   // RNE fp32 -> bf16
  return (unsigned short)(x >> 16);
}

static __device__ __forceinline__ unsigned short f2h(float f) {
  _Float16 h = (_Float16)f;        // RNE fp32 -> fp16
  return __builtin_bit_cast(unsigned short, h);
}

static __device__ __forceinline__ float fast_tanh(float x) {
  float e = __expf(2.0f * fabsf(x));                       // e^{2|x|}
  float t = 1.0f - 2.0f * __builtin_amdgcn_rcpf(e + 1.0f); // in [0,1)
  return copysignf(t, x);
}

// pack 8 fp16 -> 8 OCP e4m3 bytes (via f32, v_cvt_pk_fp8_f32)
static __device__ __forceinline__ long pack_fp8(half8 s) {
  int lo = __builtin_amdgcn_cvt_pk_fp8_f32((float)s[0], (float)s[1], 0, false);
  lo = __builtin_amdgcn_cvt_pk_fp8_f32((float)s[2], (float)s[3], lo, true);
  int hi = __builtin_amdgcn_cvt_pk_fp8_f32((float)s[4], (float)s[5], 0, false);
  hi = __builtin_amdgcn_cvt_pk_fp8_f32((float)s[6], (float)s[7], hi, true);
  return (long)(unsigned)lo | ((long)hi << 32);
}

// async global->LDS DMA, 16B per lane. LDS dest = wave-uniform base + lane*16
// (m104); global src is per-lane. Swizzled layouts are achieved by
// PRE-SWIZZLING the global buffer in k_prep (m173 pattern), dest stays linear.
static __device__ __forceinline__ void gload_lds16(const void* g, void* l) {
  __builtin_amdgcn_global_load_lds(
      (const __attribute__((address_space(1))) unsigned int*)g,
      (__attribute__((address_space(3))) unsigned int*)l, 16, 0, 0);
}

// ---- k_prep: tour | zero matrix | W2->fp8(x16) | W1->bf16 T | xcat bf16 ----
// W2F8 / W1T / xcat are written in the LDS-swizzled order their consumers
// want, so k_proj/k_main can stage them with linear global_load_lds.
__global__ __launch_bounds__(256) void k_prep(
    const float* __restrict__ x, const float* __restrict__ W1,
    const float* __restrict__ W2, float* __restrict__ out,
    unsigned char* __restrict__ W2F8, unsigned short* __restrict__ W1T,
    unsigned short* __restrict__ xcat) {
  int e = blockIdx.x * 256 + threadIdx.x;   // grid covers 1198080
  if (e < 2048) {
    out[e] = (float)(e & 255);              // improved_tour rows = arange
  } else if (e < 526336) {
    out[e] = 0.f;                           // zero matrix (uncovered tiles)
  } else if (e < 542720) {
    int t = e - 526336;                     // 16384 k-pairs of W2
    int p = t >> 7, n = t & 127;            // p = k/2, n = out channel
    float f0 = W2[(2 * p) * 128 + n] * 16.f;       // x16: into e4m3 normal range
    float f1 = W2[(2 * p + 1) * 128 + n] * 16.f;
    int v2 = __builtin_amdgcn_cvt_pk_fp8_f32(f0, f1, 0, false);
    // swizzled byte col: chunk v=(2p)>>4 xored with row&15, offset (2p)&15
    int col = 2 * p;
    int sw = (((col >> 4) ^ (n & 15)) << 4) | (col & 15);
    *(unsigned short*)(W2F8 + n * 256 + sw) = (unsigned short)(v2 & 0xffff);
  } else if (e < 673792) {
    int e3 = e - 542720;                    // 131072: W1T [512 n][256 k]
    int n = e3 >> 8, k = e3 & 255;
    int v = k >> 3;                         // 8-ushort (16B) chunk id 0..31
    int sw = (((v & 16) | ((v ^ (n & 15)) & 15)) << 3) | (k & 7);
    W1T[(n << 8) + sw] = f2bf(W1[((k + (n & 256)) << 8) + (n & 255)]);
  } else {
    int e4 = e - 673792;                    // 524288: xcat [2048 r][256 k]
    int r = e4 >> 8, k = e4 & 255;
    int v = k >> 3;
    int sw = (((v & 16) | ((v ^ (r & 15)) & 15)) << 3) | (k & 7);
    int pos = r & 255;
    int pos2 = (k < 128) ? pos : ((pos + 1) & 255);
    xcat[(r << 8) + sw] = f2bf(x[(((r >> 8) << 8) + pos2) * 128 + (k & 127)]);
  }
}

// ---- k_proj: MFMA GEMM  [2048 rows x 256 K] @ [K x 512 ch] -> PiH | PjH ----
// Staging via global_load_lds (linear dest; sources pre-swizzled by k_prep).
__global__ __launch_bounds__(256) void k_proj(
    const unsigned short* __restrict__ xcat, const unsigned short* __restrict__ W1T,
    const float* __restrict__ b1, unsigned short* __restrict__ PiH,
    unsigned short* __restrict__ PjH) {
  const int mg = blockIdx.x >> 3;       // 0..31 row-tile
  const int ng = blockIdx.x & 7;        // 0..7 channel-tile
  const int tid = threadIdx.x;
  const int wr = tid >> 6, lane = tid & 63, quad = lane >> 4, l15 = lane & 15;

  __shared__ unsigned short As[64 * 256];   // 32KB rows tile (swizzled)
  __shared__ unsigned short Bs[64 * 256];   // 32KB W1T tile (swizzled)

  const unsigned short* Asrc = xcat + mg * 64 * 256;
  const unsigned short* Bsrc = W1T + ng * 64 * 256;
#pragma unroll
  for (int it = 0; it < 8; ++it) {
    const int c = it * 256 + wr * 64 + lane;     // 16B chunk id 0..2047
    gload_lds16(Asrc + c * 8, &As[(it * 256 + wr * 64) * 8]);
    gload_lds16(Bsrc + c * 8, &Bs[(it * 256 + wr * 64) * 8]);
  }
  __syncthreads();   // drains the DMA (compiler emits vmcnt(0) before barrier)

  floatx4 acc[4];
#pragma unroll
  for (int mt = 0; mt < 4; ++mt) acc[mt] = (floatx4)0.f;

  const char* Ab = (const char*)As;
  const char* Bb = (const char*)Bs + wr * 16 * 512;
  const int base_sw = l15 * 512 + ((quad ^ l15) << 4);

#pragma unroll
  for (int ks = 0; ks < 8; ++ks) {
    const int swz = base_sw ^ (ks << 6);
    short8 bfr = *(const short8*)(Bb + swz);
#pragma unroll
    for (int mt = 0; mt < 4; ++mt) {
      short8 afr = *(const short8*)(Ab + mt * 8192 + swz);
      acc[mt] = __builtin_amdgcn_mfma_f32_16x16x32_bf16(afr, bfr, acc[mt], 0, 0, 0);
    }
  }

  const int ch = ng * 64 + wr * 16 + l15;          // 0..511 (wave-uniform side)
  const float bias = (ch < 256) ? b1[ch] : 0.f;
  unsigned short* dst = (ch < 256) ? PiH : PjH;
  const int chan = ch & 255;
#pragma unroll
  for (int mt = 0; mt < 4; ++mt)
#pragma unroll
    for (int r = 0; r < 4; ++r) {
      int row = mg * 64 + mt * 16 + quad * 4 + r;  // global row b*256+pos
      dst[row * 256 + chan] = f2h(acc[mt][r] + bias);
    }
}

// ---- k_main: persistent-grid packed items + fp8 pair-GEMM. -----------------
// 9088 items (1136/b x 8b). Grid 1024 x 256thr, __launch_bounds__(256,4):
// 4 blocks/CU (128KB LDS), 16 waves/CU. R1's spill disaster (VGPR cap 128 vs
// ~170 live -> 152MB scratch writes) is fixed STRUCTURALLY:
//   * acc[2][8] (64 regs) -> two n-half passes with acc[2][4] (32 regs)
//   * A-frags for ALL 8 ks built up front (aF0/aF1 = 32 regs) so they
//     survive both halves; the 24 Pi/Pj uint4 loads issue as one batch.
// Peak live ~= 32 aF + 32 acc + 8 bfr + 8 p + ~20 temps < 128 -> no spill.
__global__ __launch_bounds__(256, 4) void k_main(
    const unsigned short* __restrict__ PiH, const unsigned short* __restrict__ PjH,
    const unsigned char* __restrict__ W2F8, const float* __restrict__ b2,
    const float* __restrict__ W3, const float* __restrict__ b3,
    float* __restrict__ outm) {
  const int tid = threadIdx.x;
  const int wr = tid >> 6;              // wave 0..3
  const int lane = tid & 63, quad = lane >> 4, l15 = lane & 15;

  __shared__ unsigned char W2s[128 * 256];   // 32KB fp8, [n][k'] swizzled

  // stage 32KB via DMA: 2048 16B chunks, linear dest (source pre-swizzled)
#pragma unroll
  for (int it = 0; it < 8; ++it) {
    const int c = it * 256 + wr * 64 + lane;
    gload_lds16(W2F8 + c * 16, &W2s[(it * 256 + wr * 64) * 16]);
  }
  __syncthreads();

  const char* W2base = (const char*)&W2s[0];
  const int base_sw = l15 * 256 + ((((quad >> 1) ^ l15) & 15) << 4) + ((quad & 1) << 3);
  const float b3v = b3[0];
  const float s16 = 0.0625f;               // undo W2 x16 scale

#pragma unroll 1
  for (int e2 = blockIdx.x * 4 + wr; e2 < 9088; e2 += 4096) {
    // decode packed item e2 -> (b, jt, i)   [wave-uniform]
    const int b = (int)(((unsigned)e2 * 14769u) >> 24);   // e2 / 1136
    const int e = e2 - b * 1136;
    int jt = 0, base = 0;
    if (e >= 30)  { jt = 1; base = 30;  }
    if (e >= 92)  { jt = 2; base = 92;  }
    if (e >= 186) { jt = 3; base = 186; }
    if (e >= 312) { jt = 4; base = 312; }
    if (e >= 470) { jt = 5; base = 470; }
    if (e >= 660) { jt = 6; base = 660; }
    if (e >= 882) { jt = 7; base = 882; }
    const int i = e - base;                    // 0 .. jt*32+29

    const unsigned short* Pjb = PjH + ((b << 8) + jt * 32 + l15) * 256 + quad * 8;
    const unsigned short* PiRow = PiH + ((b << 8) + i) * 256 + quad * 8;

    // ---- build phase: all 8 ks A-frag pairs (relu(Pi+Pj) -> e4m3) ----
    long aF0[8], aF1[8];
#pragma unroll
    for (int ks = 0; ks < 8; ++ks) {
      union U4 { uint4 v; half8 h; } pi, pj0, pj1;
      pi.v  = *(const uint4*)(PiRow + ks * 32);
      pj0.v = *(const uint4*)(Pjb + ks * 32);
      pj1.v = *(const uint4*)(Pjb + 4096 + ks * 32);   // mt=1: +16 rows
      const half8 s0 = __builtin_elementwise_max(pi.h + pj0.h, (half8)(_Float16)0);
      const half8 s1 = __builtin_elementwise_max(pi.h + pj1.h, (half8)(_Float16)0);
      aF0[ks] = pack_fp8(s0);
      aF1[ks] = pack_fp8(s1);
    }

    float p[2][4];                           // persistent partial sums
#pragma unroll
    for (int mt = 0; mt < 2; ++mt)
#pragma unroll
      for (int r = 0; r < 4; ++r) p[mt][r] = 0.f;

    // ---- two n-half passes: acc[2][4] (32 regs) reused ----
#pragma unroll
    for (int h = 0; h < 2; ++h) {
      floatx4 acc[2][4];
#pragma unroll
      for (int mt = 0; mt < 2; ++mt)
#pragma unroll
        for (int nt = 0; nt < 4; ++nt) acc[mt][nt] = (floatx4)0.f;

#pragma unroll
      for (int ks = 0; ks < 8; ++ks) {
        const char* baddr = W2base + (base_sw ^ (ks << 5)) + h * 16384;
        long bfr[4];
#pragma unroll
        for (int nt = 0; nt < 4; ++nt) bfr[nt] = *(const long*)(baddr + nt * 4096);
        __builtin_amdgcn_s_setprio(1);
#pragma unroll
        for (int nt = 0; nt < 4; ++nt) {
          acc[0][nt] = __builtin_amdgcn_mfma_f32_16x16x32_fp8_fp8(aF0[ks], bfr[nt], acc[0][nt], 0, 0, 0);
          acc[1][nt] = __builtin_amdgcn_mfma_f32_16x16x32_fp8_fp8(aF1[ks], bfr[nt], acc[1][nt], 0, 0, 0);
        }
        __builtin_amdgcn_s_setprio(0);
      }

      // partial epilogue for this n-half: relu(C/16 + b2) * W3 into p
#pragma unroll
      for (int mt = 0; mt < 2; ++mt)
#pragma unroll
        for (int nt = 0; nt < 4; ++nt) {
          const int ntg = h * 4 + nt;
          float w3v = W3[ntg * 16 + l15];
          float b2v = b2[ntg * 16 + l15];
          floatx4 a = acc[mt][nt];
          p[mt][0] += fmaxf(fmaf(a[0], s16, b2v), 0.f) * w3v;
          p[mt][1] += fmaxf(fmaf(a[1], s16, b2v), 0.f) * w3v;
          p[mt][2] += fmaxf(fmaf(a[2], s16, b2v), 0.f) * w3v;
          p[mt][3] += fmaxf(fmaf(a[3], s16, b2v), 0.f) * w3v;
        }
    }

    // reduce over the 16 n-cols per quad, then tanh + mask + store
    float* orow = outm + ((b << 8) + i) * 256 + jt * 32;
#pragma unroll
    for (int mt = 0; mt < 2; ++mt) {
      float p0 = p[mt][0], p1 = p[mt][1], p2 = p[mt][2], p3 = p[mt][3];
#pragma unroll
      for (int m = 8; m >= 1; m >>= 1) {
        p0 += __shfl_xor(p0, m, 16);
        p1 += __shfl_xor(p1, m, 16);
        p2 += __shfl_xor(p2, m, 16);
        p3 += __shfl_xor(p3, m, 16);
      }
      if (l15 == 0) {
        const int jl = jt * 32 + mt * 16 + quad * 4;   // global j of reg 0
        float ps[4] = {p0, p1, p2, p3};
#pragma unroll
        for (int r = 0; r < 4; ++r) {
          int j = jl + r;
          float sc = fast_tanh(ps[r] + b3v);
          bool valid = (j >= i + 2) && (j - i != 255);
          orow[mt * 16 + quad * 4 + r] = valid ? sc : 0.f;
        }
      }
    }
  }
}

extern "C" void kernel_launch(void* const* d_in, const int* in_sizes, int n_in,
                              void* d_out, int out_size, void* d_ws, size_t ws_size,
                              hipStream_t stream) {
  const float* x  = (const float*)d_in[0];   // [8,256,128]
  const float* W1 = (const float*)d_in[1];   // [512,256]
  const float* b1 = (const float*)d_in[2];   // [256]
  const float* W2 = (const float*)d_in[3];   // [256,128]
  const float* b2 = (const float*)d_in[4];   // [128]
  const float* W3 = (const float*)d_in[5];   // [128]
  const float* b3 = (const float*)d_in[6];   // [1]
  float* out = (float*)d_out;

  // ws (ushort units): PiH 524288 | PjH 524288 | W1T 131072 | xcat 524288 | W2F8 32KB
  unsigned short* PiH  = (unsigned short*)d_ws;
  unsigned short* PjH  = PiH + 524288;
  unsigned short* W1T  = PjH + 524288;
  unsigned short* xcat = W1T + 131072;
  unsigned char*  W2F8 = (unsigned char*)(xcat + 524288);

  k_prep<<<4680, 256, 0, stream>>>(x, W1, W2, out, W2F8, W1T, xcat);
  k_proj<<<256, 256, 0, stream>>>(xcat, W1T, b1, PiH, PjH);
  k_main<<<1024, 256, 0, stream>>>(PiH, PjH, W2F8, b2, W3, b3, out + 2048);
}

// Round 3
// 140.310 us; speedup vs baseline: 1.1513x; 1.0739x over previous
//
#include <hip/hip_runtime.h>

// B=8, N=256, D=128, 2D=256.
// out = tour [8,256] (arange) ++ improvement_matrix [8,256,256].

typedef __attribute__((ext_vector_type(8))) short short8;
typedef __attribute__((ext_vector_type(8))) _Float16 half8;
typedef __attribute__((ext_vector_type(4))) float floatx4;

static __device__ __forceinline__ unsigned short f2bf(float f) {
  unsigned int x = __float_as_uint(f);
  x += 0x7fff + ((x >> 16) & 1);   // RNE fp32 -> bf16
  return (unsigned short)(x >> 16);
}

static __device__ __forceinline__ unsigned short f2h(float f) {
  _Float16 h = (_Float16)f;        // RNE fp32 -> fp16
  return __builtin_bit_cast(unsigned short, h);
}

static __device__ __forceinline__ float fast_tanh(float x) {
  float e = __expf(2.0f * fabsf(x));                       // e^{2|x|}
  float t = 1.0f - 2.0f * __builtin_amdgcn_rcpf(e + 1.0f); // in [0,1)
  return copysignf(t, x);
}

// pack 8 fp16 -> 8 OCP e4m3 bytes (via f32, v_cvt_pk_fp8_f32)
static __device__ __forceinline__ long pack_fp8(half8 s) {
  int lo = __builtin_amdgcn_cvt_pk_fp8_f32((float)s[0], (float)s[1], 0, false);
  lo = __builtin_amdgcn_cvt_pk_fp8_f32((float)s[2], (float)s[3], lo, true);
  int hi = __builtin_amdgcn_cvt_pk_fp8_f32((float)s[4], (float)s[5], 0, false);
  hi = __builtin_amdgcn_cvt_pk_fp8_f32((float)s[6], (float)s[7], hi, true);
  return (long)(unsigned)lo | ((long)hi << 32);
}

// async global->LDS DMA, 16B per lane. LDS dest = wave-uniform base + lane*16
// (m104); global src is per-lane. Swizzled layouts are achieved by
// PRE-SWIZZLING the global buffer in k_prep (m173 pattern), dest stays linear.
static __device__ __forceinline__ void gload_lds16(const void* g, void* l) {
  __builtin_amdgcn_global_load_lds(
      (const __attribute__((address_space(1))) unsigned int*)g,
      (__attribute__((address_space(3))) unsigned int*)l, 16, 0, 0);
}

// ---- k_prep: tour | zero matrix | W2->fp8(x16) | W1->bf16 T | xcat bf16 ----
// W2F8 / W1T / xcat are written in the LDS-swizzled order their consumers
// want, so k_proj/k_main can stage them with linear global_load_lds.
__global__ __launch_bounds__(256) void k_prep(
    const float* __restrict__ x, const float* __restrict__ W1,
    const float* __restrict__ W2, float* __restrict__ out,
    unsigned char* __restrict__ W2F8, unsigned short* __restrict__ W1T,
    unsigned short* __restrict__ xcat) {
  int e = blockIdx.x * 256 + threadIdx.x;   // grid covers 1198080
  if (e < 2048) {
    out[e] = (float)(e & 255);              // improved_tour rows = arange
  } else if (e < 526336) {
    out[e] = 0.f;                           // zero matrix (uncovered tiles)
  } else if (e < 542720) {
    int t = e - 526336;                     // 16384 k-pairs of W2
    int p = t >> 7, n = t & 127;            // p = k/2, n = out channel
    float f0 = W2[(2 * p) * 128 + n] * 16.f;       // x16: into e4m3 normal range
    float f1 = W2[(2 * p + 1) * 128 + n] * 16.f;
    int v2 = __builtin_amdgcn_cvt_pk_fp8_f32(f0, f1, 0, false);
    // swizzled byte col: chunk v=(2p)>>4 xored with row&15, offset (2p)&15
    int col = 2 * p;
    int sw = (((col >> 4) ^ (n & 15)) << 4) | (col & 15);
    *(unsigned short*)(W2F8 + n * 256 + sw) = (unsigned short)(v2 & 0xffff);
  } else if (e < 673792) {
    int e3 = e - 542720;                    // 131072: W1T [512 n][256 k]
    int n = e3 >> 8, k = e3 & 255;
    int v = k >> 3;                         // 8-ushort (16B) chunk id 0..31
    int sw = (((v & 16) | ((v ^ (n & 15)) & 15)) << 3) | (k & 7);
    W1T[(n << 8) + sw] = f2bf(W1[((k + (n & 256)) << 8) + (n & 255)]);
  } else {
    int e4 = e - 673792;                    // 524288: xcat [2048 r][256 k]
    int r = e4 >> 8, k = e4 & 255;
    int v = k >> 3;
    int sw = (((v & 16) | ((v ^ (r & 15)) & 15)) << 3) | (k & 7);
    int pos = r & 255;
    int pos2 = (k < 128) ? pos : ((pos + 1) & 255);
    xcat[(r << 8) + sw] = f2bf(x[(((r >> 8) << 8) + pos2) * 128 + (k & 127)]);
  }
}

// ---- k_proj: MFMA GEMM  [2048 rows x 256 K] @ [K x 512 ch] -> PiH | PjH ----
// Staging via global_load_lds (linear dest; sources pre-swizzled by k_prep).
__global__ __launch_bounds__(256) void k_proj(
    const unsigned short* __restrict__ xcat, const unsigned short* __restrict__ W1T,
    const float* __restrict__ b1, unsigned short* __restrict__ PiH,
    unsigned short* __restrict__ PjH) {
  const int mg = blockIdx.x >> 3;       // 0..31 row-tile
  const int ng = blockIdx.x & 7;        // 0..7 channel-tile
  const int tid = threadIdx.x;
  const int wr = tid >> 6, lane = tid & 63, quad = lane >> 4, l15 = lane & 15;

  __shared__ unsigned short As[64 * 256];   // 32KB rows tile (swizzled)
  __shared__ unsigned short Bs[64 * 256];   // 32KB W1T tile (swizzled)

  const unsigned short* Asrc = xcat + mg * 64 * 256;
  const unsigned short* Bsrc = W1T + ng * 64 * 256;
#pragma unroll
  for (int it = 0; it < 8; ++it) {
    const int c = it * 256 + wr * 64 + lane;     // 16B chunk id 0..2047
    gload_lds16(Asrc + c * 8, &As[(it * 256 + wr * 64) * 8]);
    gload_lds16(Bsrc + c * 8, &Bs[(it * 256 + wr * 64) * 8]);
  }
  __syncthreads();   // drains the DMA (compiler emits vmcnt(0) before barrier)

  floatx4 acc[4];
#pragma unroll
  for (int mt = 0; mt < 4; ++mt) acc[mt] = (floatx4)0.f;

  const char* Ab = (const char*)As;
  const char* Bb = (const char*)Bs + wr * 16 * 512;
  const int base_sw = l15 * 512 + ((quad ^ l15) << 4);

#pragma unroll
  for (int ks = 0; ks < 8; ++ks) {
    const int swz = base_sw ^ (ks << 6);
    short8 bfr = *(const short8*)(Bb + swz);
#pragma unroll
    for (int mt = 0; mt < 4; ++mt) {
      short8 afr = *(const short8*)(Ab + mt * 8192 + swz);
      acc[mt] = __builtin_amdgcn_mfma_f32_16x16x32_bf16(afr, bfr, acc[mt], 0, 0, 0);
    }
  }

  const int ch = ng * 64 + wr * 16 + l15;          // 0..511 (wave-uniform side)
  const float bias = (ch < 256) ? b1[ch] : 0.f;
  unsigned short* dst = (ch < 256) ? PiH : PjH;
  const int chan = ch & 255;
#pragma unroll
  for (int mt = 0; mt < 4; ++mt)
#pragma unroll
    for (int r = 0; r < 4; ++r) {
      int row = mg * 64 + mt * 16 + quad * 4 + r;  // global row b*256+pos
      dst[row * 256 + chan] = f2h(acc[mt][r] + bias);
    }
}

// ---- k_main: persistent-grid packed items + fp8 pair-GEMM. -----------------
// 9088 items (1136/b x 8b). Grid 768 x 256thr, __launch_bounds__(256,3):
// exactly 3 blocks/CU (96KB LDS), 12 waves/CU. R1/R2 lesson: the (256,4)
// 128-reg budget (64 arch + 64 AGPR) CANNOT hold this item's ~100-reg arch
// live set -> 130MB+ scratch spills, HBM-bound at 3.5TB/s. (256,3)'s 170-reg
// budget is the proven no-spill regime (R0 measured clean). Kept from R1/R2:
// persistent grid (W2 staged 768x not 2272x, no partial occupancy round),
// DMA staging w/ pre-swizzled source, setprio around MFMA bursts.
__global__ __launch_bounds__(256, 3) void k_main(
    const unsigned short* __restrict__ PiH, const unsigned short* __restrict__ PjH,
    const unsigned char* __restrict__ W2F8, const float* __restrict__ b2,
    const float* __restrict__ W3, const float* __restrict__ b3,
    float* __restrict__ outm) {
  const int tid = threadIdx.x;
  const int wr = tid >> 6;              // wave 0..3
  const int lane = tid & 63, quad = lane >> 4, l15 = lane & 15;

  __shared__ unsigned char W2s[128 * 256];   // 32KB fp8, [n][k'] swizzled

  // stage 32KB via DMA: 2048 16B chunks, linear dest (source pre-swizzled)
#pragma unroll
  for (int it = 0; it < 8; ++it) {
    const int c = it * 256 + wr * 64 + lane;
    gload_lds16(W2F8 + c * 16, &W2s[(it * 256 + wr * 64) * 16]);
  }
  __syncthreads();

  const char* W2base = (const char*)&W2s[0];
  const int base_sw = l15 * 256 + ((((quad >> 1) ^ l15) & 15) << 4) + ((quad & 1) << 3);
  const float b3v = b3[0];
  const float s16 = 0.0625f;               // undo W2 x16 scale

#pragma unroll 1
  for (int e2 = blockIdx.x * 4 + wr; e2 < 9088; e2 += 3072) {
    // decode packed item e2 -> (b, jt, i)   [wave-uniform]
    const int b = (int)(((unsigned)e2 * 14769u) >> 24);   // e2 / 1136
    const int e = e2 - b * 1136;
    int jt = 0, base = 0;
    if (e >= 30)  { jt = 1; base = 30;  }
    if (e >= 92)  { jt = 2; base = 92;  }
    if (e >= 186) { jt = 3; base = 186; }
    if (e >= 312) { jt = 4; base = 312; }
    if (e >= 470) { jt = 5; base = 470; }
    if (e >= 660) { jt = 6; base = 660; }
    if (e >= 882) { jt = 7; base = 882; }
    const int i = e - base;                    // 0 .. jt*32+29

    const unsigned short* Pjb = PjH + ((b << 8) + jt * 32 + l15) * 256 + quad * 8;
    const unsigned short* PiRow = PiH + ((b << 8) + i) * 256 + quad * 8;

    floatx4 acc[2][8];
#pragma unroll
    for (int mt = 0; mt < 2; ++mt)
#pragma unroll
      for (int nt = 0; nt < 8; ++nt) acc[mt][nt] = (floatx4)0.f;

    union U4 { uint4 v; half8 h; };
    U4 piR[2], pjR[2][2];
    piR[0].v = *(const uint4*)(PiRow);
    pjR[0][0].v = *(const uint4*)(Pjb);
    pjR[0][1].v = *(const uint4*)(Pjb + 4096);   // mt=1: +16 rows

#pragma unroll
    for (int ks = 0; ks < 8; ++ks) {
      const int cur = ks & 1, nxt = cur ^ 1;
      // (1) batch this iteration's 8 B-frag LDS reads -> one lgkm wait
      long bfr[8];
      const char* baddr = W2base + (base_sw ^ (ks << 5));
#pragma unroll
      for (int nt = 0; nt < 8; ++nt) bfr[nt] = *(const long*)(baddr + nt * 4096);
      // (2) depth-1 global prefetch for ks+1
      if (ks < 7) {
        piR[nxt].v = *(const uint4*)(PiRow + (ks + 1) * 32);
        pjR[nxt][0].v = *(const uint4*)(Pjb + (ks + 1) * 32);
        pjR[nxt][1].v = *(const uint4*)(Pjb + 4096 + (ks + 1) * 32);
      }
      // (3) build A-frags: packed fp16 relu(Pi+Pj), then pack to e4m3
      const half8 s0 = __builtin_elementwise_max(piR[cur].h + pjR[cur][0].h,
                                                 (half8)(_Float16)0);
      const half8 s1 = __builtin_elementwise_max(piR[cur].h + pjR[cur][1].h,
                                                 (half8)(_Float16)0);
      const long a0 = pack_fp8(s0);
      const long a1 = pack_fp8(s1);
      // (4) MFMA burst
      __builtin_amdgcn_s_setprio(1);
#pragma unroll
      for (int nt = 0; nt < 8; ++nt) {
        acc[0][nt] = __builtin_amdgcn_mfma_f32_16x16x32_fp8_fp8(a0, bfr[nt], acc[0][nt], 0, 0, 0);
        acc[1][nt] = __builtin_amdgcn_mfma_f32_16x16x32_fp8_fp8(a1, bfr[nt], acc[1][nt], 0, 0, 0);
      }
      __builtin_amdgcn_s_setprio(0);
    }

    // epilogue: score[j] = tanh(sum_n W3[n]*relu(C[j,n]/16 + b2[n]) + b3)
    float* orow = outm + ((b << 8) + i) * 256 + jt * 32;
#pragma unroll
    for (int mt = 0; mt < 2; ++mt) {
      float p0 = 0, p1 = 0, p2 = 0, p3 = 0;
#pragma unroll
      for (int nt = 0; nt < 8; ++nt) {
        float w3v = W3[nt * 16 + l15];
        float b2v = b2[nt * 16 + l15];
        floatx4 a = acc[mt][nt];
        p0 += fmaxf(fmaf(a[0], s16, b2v), 0.f) * w3v;
        p1 += fmaxf(fmaf(a[1], s16, b2v), 0.f) * w3v;
        p2 += fmaxf(fmaf(a[2], s16, b2v), 0.f) * w3v;
        p3 += fmaxf(fmaf(a[3], s16, b2v), 0.f) * w3v;
      }
#pragma unroll
      for (int m = 8; m >= 1; m >>= 1) {   // reduce over the 16 n-cols per quad
        p0 += __shfl_xor(p0, m, 16);
        p1 += __shfl_xor(p1, m, 16);
        p2 += __shfl_xor(p2, m, 16);
        p3 += __shfl_xor(p3, m, 16);
      }
      if (l15 == 0) {
        const int jl = jt * 32 + mt * 16 + quad * 4;   // global j of reg 0
        float ps[4] = {p0, p1, p2, p3};
#pragma unroll
        for (int r = 0; r < 4; ++r) {
          int j = jl + r;
          float sc = fast_tanh(ps[r] + b3v);
          bool valid = (j >= i + 2) && (j - i != 255);
          orow[mt * 16 + quad * 4 + r] = valid ? sc : 0.f;
        }
      }
    }
  }
}

extern "C" void kernel_launch(void* const* d_in, const int* in_sizes, int n_in,
                              void* d_out, int out_size, void* d_ws, size_t ws_size,
                              hipStream_t stream) {
  const float* x  = (const float*)d_in[0];   // [8,256,128]
  const float* W1 = (const float*)d_in[1];   // [512,256]
  const float* b1 = (const float*)d_in[2];   // [256]
  const float* W2 = (const float*)d_in[3];   // [256,128]
  const float* b2 = (const float*)d_in[4];   // [128]
  const float* W3 = (const float*)d_in[5];   // [128]
  const float* b3 = (const float*)d_in[6];   // [1]
  float* out = (float*)d_out;

  // ws (ushort units): PiH 524288 | PjH 524288 | W1T 131072 | xcat 524288 | W2F8 32KB
  unsigned short* PiH  = (unsigned short*)d_ws;
  unsigned short* PjH  = PiH + 524288;
  unsigned short* W1T  = PjH + 524288;
  unsigned short* xcat = W1T + 131072;
  unsigned char*  W2F8 = (unsigned char*)(xcat + 524288);

  k_prep<<<4680, 256, 0, stream>>>(x, W1, W2, out, W2F8, W1T, xcat);
  k_proj<<<256, 256, 0, stream>>>(xcat, W1T, b1, PiH, PjH);
  k_main<<<768, 256, 0, stream>>>(PiH, PjH, W2F8, b2, W3, b3, out + 2048);
}

// Round 4
// 101.550 us; speedup vs baseline: 1.5907x; 1.3817x over previous
//
#include <hip/hip_runtime.h>

// B=8, N=256, D=128, 2D=256.
// out = tour [8,256] (arange) ++ improvement_matrix [8,256,256].

typedef __attribute__((ext_vector_type(8))) short short8;
typedef __attribute__((ext_vector_type(8))) _Float16 half8;
typedef __attribute__((ext_vector_type(4))) float floatx4;

static __device__ __forceinline__ unsigned short f2bf(float f) {
  unsigned int x = __float_as_uint(f);
  x += 0x7fff + ((x >> 16) & 1);   // RNE fp32 -> bf16
  return (unsigned short)(x >> 16);
}

static __device__ __forceinline__ unsigned short f2h(float f) {
  _Float16 h = (_Float16)f;        // RNE fp32 -> fp16
  return __builtin_bit_cast(unsigned short, h);
}

static __device__ __forceinline__ float fast_tanh(float x) {
  float e = __expf(2.0f * fabsf(x));                       // e^{2|x|}
  float t = 1.0f - 2.0f * __builtin_amdgcn_rcpf(e + 1.0f); // in [0,1)
  return copysignf(t, x);
}

// pack 8 fp16 -> 8 OCP e4m3 bytes (via f32, v_cvt_pk_fp8_f32)
static __device__ __forceinline__ long pack_fp8(half8 s) {
  int lo = __builtin_amdgcn_cvt_pk_fp8_f32((float)s[0], (float)s[1], 0, false);
  lo = __builtin_amdgcn_cvt_pk_fp8_f32((float)s[2], (float)s[3], lo, true);
  int hi = __builtin_amdgcn_cvt_pk_fp8_f32((float)s[4], (float)s[5], 0, false);
  hi = __builtin_amdgcn_cvt_pk_fp8_f32((float)s[6], (float)s[7], hi, true);
  return (long)(unsigned)lo | ((long)hi << 32);
}

// async global->LDS DMA, 16B per lane. LDS dest = wave-uniform base + lane*16
// (m104); global src is per-lane. Swizzled layouts are achieved by
// PRE-SWIZZLING the global buffer in k_prep (m173 pattern), dest stays linear.
static __device__ __forceinline__ void gload_lds16(const void* g, void* l) {
  __builtin_amdgcn_global_load_lds(
      (const __attribute__((address_space(1))) unsigned int*)g,
      (__attribute__((address_space(3))) unsigned int*)l, 16, 0, 0);
}

// ---- k_prep: tour | zero matrix | W2->fp8(x16) | W1->bf16 T | xcat bf16 ----
// W2F8 / W1T / xcat are written in the LDS-swizzled order their consumers
// want, so k_proj/k_main can stage them with linear global_load_lds.
__global__ __launch_bounds__(256) void k_prep(
    const float* __restrict__ x, const float* __restrict__ W1,
    const float* __restrict__ W2, float* __restrict__ out,
    unsigned char* __restrict__ W2F8, unsigned short* __restrict__ W1T,
    unsigned short* __restrict__ xcat) {
  int e = blockIdx.x * 256 + threadIdx.x;   // grid covers 1198080
  if (e < 2048) {
    out[e] = (float)(e & 255);              // improved_tour rows = arange
  } else if (e < 526336) {
    out[e] = 0.f;                           // zero matrix (uncovered tiles)
  } else if (e < 542720) {
    int t = e - 526336;                     // 16384 k-pairs of W2
    int p = t >> 7, n = t & 127;            // p = k/2, n = out channel
    float f0 = W2[(2 * p) * 128 + n] * 16.f;       // x16: into e4m3 normal range
    float f1 = W2[(2 * p + 1) * 128 + n] * 16.f;
    int v2 = __builtin_amdgcn_cvt_pk_fp8_f32(f0, f1, 0, false);
    // swizzled byte col: chunk v=(2p)>>4 xored with row&15, offset (2p)&15
    int col = 2 * p;
    int sw = (((col >> 4) ^ (n & 15)) << 4) | (col & 15);
    *(unsigned short*)(W2F8 + n * 256 + sw) = (unsigned short)(v2 & 0xffff);
  } else if (e < 673792) {
    int e3 = e - 542720;                    // 131072: W1T [512 n][256 k]
    int n = e3 >> 8, k = e3 & 255;
    int v = k >> 3;                         // 8-ushort (16B) chunk id 0..31
    int sw = (((v & 16) | ((v ^ (n & 15)) & 15)) << 3) | (k & 7);
    W1T[(n << 8) + sw] = f2bf(W1[((k + (n & 256)) << 8) + (n & 255)]);
  } else {
    int e4 = e - 673792;                    // 524288: xcat [2048 r][256 k]
    int r = e4 >> 8, k = e4 & 255;
    int v = k >> 3;
    int sw = (((v & 16) | ((v ^ (r & 15)) & 15)) << 3) | (k & 7);
    int pos = r & 255;
    int pos2 = (k < 128) ? pos : ((pos + 1) & 255);
    xcat[(r << 8) + sw] = f2bf(x[(((r >> 8) << 8) + pos2) * 128 + (k & 127)]);
  }
}

// ---- k_proj: MFMA GEMM  [2048 rows x 256 K] @ [K x 512 ch] -> PiH | PjH ----
// Staging via global_load_lds (linear dest; sources pre-swizzled by k_prep).
__global__ __launch_bounds__(256) void k_proj(
    const unsigned short* __restrict__ xcat, const unsigned short* __restrict__ W1T,
    const float* __restrict__ b1, unsigned short* __restrict__ PiH,
    unsigned short* __restrict__ PjH) {
  const int mg = blockIdx.x >> 3;       // 0..31 row-tile
  const int ng = blockIdx.x & 7;        // 0..7 channel-tile
  const int tid = threadIdx.x;
  const int wr = tid >> 6, lane = tid & 63, quad = lane >> 4, l15 = lane & 15;

  __shared__ unsigned short As[64 * 256];   // 32KB rows tile (swizzled)
  __shared__ unsigned short Bs[64 * 256];   // 32KB W1T tile (swizzled)

  const unsigned short* Asrc = xcat + mg * 64 * 256;
  const unsigned short* Bsrc = W1T + ng * 64 * 256;
#pragma unroll
  for (int it = 0; it < 8; ++it) {
    const int c = it * 256 + wr * 64 + lane;     // 16B chunk id 0..2047
    gload_lds16(Asrc + c * 8, &As[(it * 256 + wr * 64) * 8]);
    gload_lds16(Bsrc + c * 8, &Bs[(it * 256 + wr * 64) * 8]);
  }
  __syncthreads();   // drains the DMA (compiler emits vmcnt(0) before barrier)

  floatx4 acc[4];
#pragma unroll
  for (int mt = 0; mt < 4; ++mt) acc[mt] = (floatx4)0.f;

  const char* Ab = (const char*)As;
  const char* Bb = (const char*)Bs + wr * 16 * 512;
  const int base_sw = l15 * 512 + ((quad ^ l15) << 4);

#pragma unroll
  for (int ks = 0; ks < 8; ++ks) {
    const int swz = base_sw ^ (ks << 6);
    short8 bfr = *(const short8*)(Bb + swz);
#pragma unroll
    for (int mt = 0; mt < 4; ++mt) {
      short8 afr = *(const short8*)(Ab + mt * 8192 + swz);
      acc[mt] = __builtin_amdgcn_mfma_f32_16x16x32_bf16(afr, bfr, acc[mt], 0, 0, 0);
    }
  }

  const int ch = ng * 64 + wr * 16 + l15;          // 0..511 (wave-uniform side)
  const float bias = (ch < 256) ? b1[ch] : 0.f;
  unsigned short* dst = (ch < 256) ? PiH : PjH;
  const int chan = ch & 255;
#pragma unroll
  for (int mt = 0; mt < 4; ++mt)
#pragma unroll
    for (int r = 0; r < 4; ++r) {
      int row = mg * 64 + mt * 16 + quad * 4 + r;  // global row b*256+pos
      dst[row * 256 + chan] = f2h(acc[mt][r] + bias);
    }
}

// ---- k_main: one item per wave (NO persistent loop) + fp8 pair-GEMM. -------
// 9088 items (1136/b x 8b); grid 2272 x 256thr (4 waves, 1 item each).
// R1-R3 lesson: wrapping this body in a persistent `#pragma unroll 1` loop
// makes the compiler stop fully unrolling the inner pipelined chain ->
// piR[cur]/pjR[cur] become runtime-indexed -> local memory -> 80-150MB of
// scratch traffic (rule #20). One-item-per-wave at top level is the proven
// clean regime (R0). Kept: DMA W2 staging (pre-swizzled source), setprio
// around MFMA bursts. New: bfr double-buffer -- issue ks+1's 8 ds_read_b64
// during ks's compute so the lgkm wait is off the critical path (+32 VGPR,
// fits the (256,3) 170-reg budget: ~64 acc + ~110 arch).
__global__ __launch_bounds__(256, 3) void k_main(
    const unsigned short* __restrict__ PiH, const unsigned short* __restrict__ PjH,
    const unsigned char* __restrict__ W2F8, const float* __restrict__ b2,
    const float* __restrict__ W3, const float* __restrict__ b3,
    float* __restrict__ outm) {
  const int tid = threadIdx.x;
  const int wr = tid >> 6;              // wave 0..3
  const int lane = tid & 63, quad = lane >> 4, l15 = lane & 15;

  __shared__ unsigned char W2s[128 * 256];   // 32KB fp8, [n][k'] swizzled

  // stage 32KB via DMA: 2048 16B chunks, linear dest (source pre-swizzled)
#pragma unroll
  for (int it = 0; it < 8; ++it) {
    const int c = it * 256 + wr * 64 + lane;
    gload_lds16(W2F8 + c * 16, &W2s[(it * 256 + wr * 64) * 16]);
  }
  __syncthreads();

  // decode packed item e2 -> (b, jt, i)   [wave-uniform]
  const int e2 = blockIdx.x * 4 + wr;        // 0..9087
  const int b = (int)(((unsigned)e2 * 14769u) >> 24);   // e2 / 1136
  const int e = e2 - b * 1136;
  int jt = 0, base = 0;
  if (e >= 30)  { jt = 1; base = 30;  }
  if (e >= 92)  { jt = 2; base = 92;  }
  if (e >= 186) { jt = 3; base = 186; }
  if (e >= 312) { jt = 4; base = 312; }
  if (e >= 470) { jt = 5; base = 470; }
  if (e >= 660) { jt = 6; base = 660; }
  if (e >= 882) { jt = 7; base = 882; }
  const int i = e - base;                    // 0 .. jt*32+29

  const char* W2base = (const char*)&W2s[0];
  const int base_sw = l15 * 256 + ((((quad >> 1) ^ l15) & 15) << 4) + ((quad & 1) << 3);
  const unsigned short* Pjb = PjH + ((b << 8) + jt * 32 + l15) * 256 + quad * 8;
  const unsigned short* PiRow = PiH + ((b << 8) + i) * 256 + quad * 8;

  floatx4 acc[2][8];
#pragma unroll
  for (int mt = 0; mt < 2; ++mt)
#pragma unroll
    for (int nt = 0; nt < 8; ++nt) acc[mt][nt] = (floatx4)0.f;

  union U4 { uint4 v; half8 h; };
  U4 piR[2], pjR[2][2];
  piR[0].v = *(const uint4*)(PiRow);
  pjR[0][0].v = *(const uint4*)(Pjb);
  pjR[0][1].v = *(const uint4*)(Pjb + 4096);   // mt=1: +16 rows

  // B-frag double buffer: prologue loads ks=0's 8 frags
  long bfrA[8], bfrB[8];
  {
    const char* b0 = W2base + base_sw;
#pragma unroll
    for (int nt = 0; nt < 8; ++nt) bfrA[nt] = *(const long*)(b0 + nt * 4096);
  }

#pragma unroll
  for (int ks = 0; ks < 8; ++ks) {
    const int cur = ks & 1, nxt = cur ^ 1;
    // (1) issue NEXT iteration's 8 B-frag ds_reads (latency hidden under
    //     this iteration's VALU + MFMA; lgkm wait lands off critical path)
    if (ks < 7) {
      const char* bn = W2base + (base_sw ^ ((ks + 1) << 5));
#pragma unroll
      for (int nt = 0; nt < 8; ++nt)
        ((ks & 1) ? bfrA : bfrB)[nt] = *(const long*)(bn + nt * 4096);
    }
    // (2) depth-1 global prefetch for ks+1
    if (ks < 7) {
      piR[nxt].v = *(const uint4*)(PiRow + (ks + 1) * 32);
      pjR[nxt][0].v = *(const uint4*)(Pjb + (ks + 1) * 32);
      pjR[nxt][1].v = *(const uint4*)(Pjb + 4096 + (ks + 1) * 32);
    }
    // (3) build A-frags: packed fp16 relu(Pi+Pj), then pack to e4m3
    const half8 s0 = __builtin_elementwise_max(piR[cur].h + pjR[cur][0].h,
                                               (half8)(_Float16)0);
    const half8 s1 = __builtin_elementwise_max(piR[cur].h + pjR[cur][1].h,
                                               (half8)(_Float16)0);
    const long a0 = pack_fp8(s0);
    const long a1 = pack_fp8(s1);
    // (4) MFMA burst on the CURRENT buffer (reads issued one iter ago)
    const long* bc = (ks & 1) ? bfrB : bfrA;
    __builtin_amdgcn_s_setprio(1);
#pragma unroll
    for (int nt = 0; nt < 8; ++nt) {
      acc[0][nt] = __builtin_amdgcn_mfma_f32_16x16x32_fp8_fp8(a0, bc[nt], acc[0][nt], 0, 0, 0);
      acc[1][nt] = __builtin_amdgcn_mfma_f32_16x16x32_fp8_fp8(a1, bc[nt], acc[1][nt], 0, 0, 0);
    }
    __builtin_amdgcn_s_setprio(0);
  }

  // epilogue: score[j] = tanh(sum_n W3[n]*relu(C[j,n]/16 + b2[n]) + b3)
  float* orow = outm + ((b << 8) + i) * 256 + jt * 32;
  const float b3v = b3[0];
  const float s16 = 0.0625f;               // undo W2 x16 scale
#pragma unroll
  for (int mt = 0; mt < 2; ++mt) {
    float p0 = 0, p1 = 0, p2 = 0, p3 = 0;
#pragma unroll
    for (int nt = 0; nt < 8; ++nt) {
      float w3v = W3[nt * 16 + l15];
      float b2v = b2[nt * 16 + l15];
      floatx4 a = acc[mt][nt];
      p0 += fmaxf(fmaf(a[0], s16, b2v), 0.f) * w3v;
      p1 += fmaxf(fmaf(a[1], s16, b2v), 0.f) * w3v;
      p2 += fmaxf(fmaf(a[2], s16, b2v), 0.f) * w3v;
      p3 += fmaxf(fmaf(a[3], s16, b2v), 0.f) * w3v;
    }
#pragma unroll
    for (int m = 8; m >= 1; m >>= 1) {   // reduce over the 16 n-cols per quad
      p0 += __shfl_xor(p0, m, 16);
      p1 += __shfl_xor(p1, m, 16);
      p2 += __shfl_xor(p2, m, 16);
      p3 += __shfl_xor(p3, m, 16);
    }
    if (l15 == 0) {
      const int jl = jt * 32 + mt * 16 + quad * 4;   // global j of reg 0
      float ps[4] = {p0, p1, p2, p3};
#pragma unroll
      for (int r = 0; r < 4; ++r) {
        int j = jl + r;
        float sc = fast_tanh(ps[r] + b3v);
        bool valid = (j >= i + 2) && (j - i != 255);
        orow[mt * 16 + quad * 4 + r] = valid ? sc : 0.f;
      }
    }
  }
}

extern "C" void kernel_launch(void* const* d_in, const int* in_sizes, int n_in,
                              void* d_out, int out_size, void* d_ws, size_t ws_size,
                              hipStream_t stream) {
  const float* x  = (const float*)d_in[0];   // [8,256,128]
  const float* W1 = (const float*)d_in[1];   // [512,256]
  const float* b1 = (const float*)d_in[2];   // [256]
  const float* W2 = (const float*)d_in[3];   // [256,128]
  const float* b2 = (const float*)d_in[4];   // [128]
  const float* W3 = (const float*)d_in[5];   // [128]
  const float* b3 = (const float*)d_in[6];   // [1]
  float* out = (float*)d_out;

  // ws (ushort units): PiH 524288 | PjH 524288 | W1T 131072 | xcat 524288 | W2F8 32KB
  unsigned short* PiH  = (unsigned short*)d_ws;
  unsigned short* PjH  = PiH + 524288;
  unsigned short* W1T  = PjH + 524288;
  unsigned short* xcat = W1T + 131072;
  unsigned char*  W2F8 = (unsigned char*)(xcat + 524288);

  k_prep<<<4680, 256, 0, stream>>>(x, W1, W2, out, W2F8, W1T, xcat);
  k_proj<<<256, 256, 0, stream>>>(xcat, W1T, b1, PiH, PjH);
  k_main<<<2272, 256, 0, stream>>>(PiH, PjH, W2F8, b2, W3, b3, out + 2048);
}

// Round 5
// 96.959 us; speedup vs baseline: 1.6660x; 1.0474x over previous
//
#include <hip/hip_runtime.h>

// B=8, N=256, D=128, 2D=256.
// out = tour [8,256] (arange) ++ improvement_matrix [8,256,256].

typedef __attribute__((ext_vector_type(8))) short short8;
typedef __attribute__((ext_vector_type(8))) _Float16 half8;
typedef __attribute__((ext_vector_type(4))) float floatx4;

static __device__ __forceinline__ unsigned short f2bf(float f) {
  unsigned int x = __float_as_uint(f);
  x += 0x7fff + ((x >> 16) & 1);   // RNE fp32 -> bf16
  return (unsigned short)(x >> 16);
}

static __device__ __forceinline__ unsigned short f2h(float f) {
  _Float16 h = (_Float16)f;        // RNE fp32 -> fp16
  return __builtin_bit_cast(unsigned short, h);
}

static __device__ __forceinline__ float fast_tanh(float x) {
  float e = __expf(2.0f * fabsf(x));                       // e^{2|x|}
  float t = 1.0f - 2.0f * __builtin_amdgcn_rcpf(e + 1.0f); // in [0,1)
  return copysignf(t, x);
}

// pack 8 fp16 -> 8 OCP e4m3 bytes (via f32, v_cvt_pk_fp8_f32)
static __device__ __forceinline__ long pack_fp8(half8 s) {
  int lo = __builtin_amdgcn_cvt_pk_fp8_f32((float)s[0], (float)s[1], 0, false);
  lo = __builtin_amdgcn_cvt_pk_fp8_f32((float)s[2], (float)s[3], lo, true);
  int hi = __builtin_amdgcn_cvt_pk_fp8_f32((float)s[4], (float)s[5], 0, false);
  hi = __builtin_amdgcn_cvt_pk_fp8_f32((float)s[6], (float)s[7], hi, true);
  return (long)(unsigned)lo | ((long)hi << 32);
}

// async global->LDS DMA, 16B per lane. LDS dest = wave-uniform base + lane*16
// (m104); global src is per-lane. Swizzled layouts are achieved by
// PRE-SWIZZLING the global buffer (m173 pattern), dest stays linear.
static __device__ __forceinline__ void gload_lds16(const void* g, void* l) {
  __builtin_amdgcn_global_load_lds(
      (const __attribute__((address_space(1))) unsigned int*)g,
      (__attribute__((address_space(3))) unsigned int*)l, 16, 0, 0);
}

// ---- k_prep: tour | zero matrix | W2->fp8 paired | W1->bf16 T | xcat bf16 --
// W2F8 layout (NEW, paired for b128 B-frag reads): channel n -> np=n>>4,
// q=np>>1, which=np&1, l=n&15; k-chunk c=k>>3 swizzled c'=(c&16)|((c^l)&15).
// byte = q*8192 + l*512 + c'*16 + which*8 + (k&7). One ds_read_b128 then
// yields the 8B K=32 frags of BOTH chans nt=2q (lo) and nt=2q+1 (hi).
__global__ __launch_bounds__(256) void k_prep(
    const float* __restrict__ x, const float* __restrict__ W1,
    const float* __restrict__ W2, float* __restrict__ out,
    unsigned char* __restrict__ W2F8, unsigned short* __restrict__ W1T,
    unsigned short* __restrict__ xcat) {
  int e = blockIdx.x * 256 + threadIdx.x;   // grid covers 1198080
  if (e < 2048) {
    out[e] = (float)(e & 255);              // improved_tour rows = arange
  } else if (e < 526336) {
    out[e] = 0.f;                           // zero matrix (uncovered tiles)
  } else if (e < 542720) {
    int t = e - 526336;                     // 16384 k-pairs of W2
    int p = t >> 7, n = t & 127;            // p = k/2, n = out channel
    float f0 = W2[(2 * p) * 128 + n] * 16.f;       // x16: into e4m3 normal range
    float f1 = W2[(2 * p + 1) * 128 + n] * 16.f;
    int v2 = __builtin_amdgcn_cvt_pk_fp8_f32(f0, f1, 0, false);
    int q = n >> 5, which = (n >> 4) & 1, l = n & 15;
    int c = p >> 2, off = (p & 3) * 2;      // c = (2p)>>4? no: k-chunk = k>>3 = p>>2
    int cs = (c & 16) | ((c ^ l) & 15);
    *(unsigned short*)(W2F8 + q * 8192 + l * 512 + cs * 16 + which * 8 + off) =
        (unsigned short)(v2 & 0xffff);
  } else if (e < 673792) {
    int e3 = e - 542720;                    // 131072: W1T [512 n][256 k]
    int n = e3 >> 8, k = e3 & 255;
    int v = k >> 3;                         // 8-ushort (16B) chunk id 0..31
    int sw = (((v & 16) | ((v ^ (n & 15)) & 15)) << 3) | (k & 7);
    W1T[(n << 8) + sw] = f2bf(W1[((k + (n & 256)) << 8) + (n & 255)]);
  } else {
    int e4 = e - 673792;                    // 524288: xcat [2048 r][256 k]
    int r = e4 >> 8, k = e4 & 255;
    int v = k >> 3;
    int sw = (((v & 16) | ((v ^ (r & 15)) & 15)) << 3) | (k & 7);
    int pos = r & 255;
    int pos2 = (k < 128) ? pos : ((pos + 1) & 255);
    xcat[(r << 8) + sw] = f2bf(x[(((r >> 8) << 8) + pos2) * 128 + (k & 127)]);
  }
}

// ---- k_proj: MFMA GEMM  [2048 rows x 256 K] @ [K x 512 ch] -> PiH | PjH ----
// PiH stays LINEAR (k_main broadcasts rows). PjH is written CHUNK-SWIZZLED
// per row (key = row&15) so k_main can DMA the 32-row jt tile linearly into
// LDS and ds_read conflict-even: chunk c=chan>>3 -> c'=(c&16)|((c^(row&15))&15).
__global__ __launch_bounds__(256) void k_proj(
    const unsigned short* __restrict__ xcat, const unsigned short* __restrict__ W1T,
    const float* __restrict__ b1, unsigned short* __restrict__ PiH,
    unsigned short* __restrict__ PjH) {
  const int mg = blockIdx.x >> 3;       // 0..31 row-tile
  const int ng = blockIdx.x & 7;        // 0..7 channel-tile
  const int tid = threadIdx.x;
  const int wr = tid >> 6, lane = tid & 63, quad = lane >> 4, l15 = lane & 15;

  __shared__ unsigned short As[64 * 256];   // 32KB rows tile (swizzled)
  __shared__ unsigned short Bs[64 * 256];   // 32KB W1T tile (swizzled)

  const unsigned short* Asrc = xcat + mg * 64 * 256;
  const unsigned short* Bsrc = W1T + ng * 64 * 256;
#pragma unroll
  for (int it = 0; it < 8; ++it) {
    const int c = it * 256 + wr * 64 + lane;     // 16B chunk id 0..2047
    gload_lds16(Asrc + c * 8, &As[(it * 256 + wr * 64) * 8]);
    gload_lds16(Bsrc + c * 8, &Bs[(it * 256 + wr * 64) * 8]);
  }
  __syncthreads();   // drains the DMA (compiler emits vmcnt(0) before barrier)

  floatx4 acc[4];
#pragma unroll
  for (int mt = 0; mt < 4; ++mt) acc[mt] = (floatx4)0.f;

  const char* Ab = (const char*)As;
  const char* Bb = (const char*)Bs + wr * 16 * 512;
  const int base_sw = l15 * 512 + ((quad ^ l15) << 4);

#pragma unroll
  for (int ks = 0; ks < 8; ++ks) {
    const int swz = base_sw ^ (ks << 6);
    short8 bfr = *(const short8*)(Bb + swz);
#pragma unroll
    for (int mt = 0; mt < 4; ++mt) {
      short8 afr = *(const short8*)(Ab + mt * 8192 + swz);
      acc[mt] = __builtin_amdgcn_mfma_f32_16x16x32_bf16(afr, bfr, acc[mt], 0, 0, 0);
    }
  }

  const int ch = ng * 64 + wr * 16 + l15;          // 0..511 (wave-uniform side)
  const float bias = (ch < 256) ? b1[ch] : 0.f;
  const bool isPi = (ch < 256);
  unsigned short* dst = isPi ? PiH : PjH;
  const int chan = ch & 255;
  const int ck = chan >> 3, coff = chan & 7;
#pragma unroll
  for (int mt = 0; mt < 4; ++mt)
#pragma unroll
    for (int r = 0; r < 4; ++r) {
      int row = mg * 64 + mt * 16 + quad * 4 + r;  // global row b*256+pos
      int cpos;
      if (isPi) cpos = chan;
      else {
        int cs = (ck & 16) | ((ck ^ (row & 15)) & 15);
        cpos = cs * 8 + coff;
      }
      dst[row * 256 + cpos] = f2h(acc[mt][r] + bias);
    }
}

// ---- k_main: same-jt blocks, fully LDS-resident inner loop. ----------------
// Grid 2304 x 256thr: per b (8) there are 288 blocks; (b,jt) group g has
// (g+1)*8 blocks = (g+1)*32 items (2 pad items per group whose valid-mask is
// provably empty -> they write zeros == k_prep's fill, race-free).
// Block stages: W2 32KB (paired/swizzled) + Pj jt-tile 16KB (swizzled, DMA
// linear from pre-swizzled PjH) + 4 Pi rows 4KB = 52KB LDS, 3 blocks/CU.
// Inner loop: ZERO global loads; bfr = 4x ds_read_b128 (paired W2, was 8x
// b64); pi/pj = 3x ds_read_b128; all depth-1 double-buffered. This removes
// the L2 latency (200-500cy) that depth-1 global prefetch couldn't hide at
// 3 waves/SIMD, and halves the W2 LDS-pipe beats.
__global__ __launch_bounds__(256, 3) void k_main(
    const unsigned short* __restrict__ PiH, const unsigned short* __restrict__ PjH,
    const unsigned char* __restrict__ W2F8, const float* __restrict__ b2,
    const float* __restrict__ W3, const float* __restrict__ b3,
    float* __restrict__ outm) {
  const int tid = threadIdx.x;
  const int wr = tid >> 6;              // wave 0..3
  const int lane = tid & 63, quad = lane >> 4, l15 = lane & 15;

  __shared__ unsigned char W2s[32768];  // paired+swizzled fp8
  __shared__ unsigned char PjS[16384];  // 32 rows x 512B, chunk-swizzled
  __shared__ unsigned char PiS[4096];   // 4 waves x 1024B (row duplicated)

  // decode block -> (b, jt, i-base)   [block-uniform except wr]
  const int bid = blockIdx.x;
  const int b = bid / 288;
  const int rem = bid - b * 288;
  int jt = 0, basej = 0;
  if (rem >= 8)   { jt = 1; basej = 8;   }
  if (rem >= 24)  { jt = 2; basej = 24;  }
  if (rem >= 48)  { jt = 3; basej = 48;  }
  if (rem >= 80)  { jt = 4; basej = 80;  }
  if (rem >= 120) { jt = 5; basej = 120; }
  if (rem >= 168) { jt = 6; basej = 168; }
  if (rem >= 224) { jt = 7; basej = 224; }
  const int i = (rem - basej) * 4 + wr;      // 0 .. (jt+1)*32-1 (2 pads/group)

  // stage W2 32KB (2048 chunks) + Pj tile 16KB (1024 chunks) + Pi row/wave
  const unsigned char* pjsrc =
      (const unsigned char*)(PjH + ((b << 8) + jt * 32) * 256);
  const unsigned char* pisrc =
      (const unsigned char*)(PiH + ((b << 8) + i) * 256);
#pragma unroll
  for (int it = 0; it < 8; ++it) {
    const int c = it * 256 + wr * 64 + lane;
    gload_lds16(W2F8 + c * 16, &W2s[(it * 256 + wr * 64) * 16]);
  }
#pragma unroll
  for (int it = 0; it < 4; ++it) {
    const int c = it * 256 + wr * 64 + lane;
    gload_lds16(pjsrc + c * 16, &PjS[(it * 256 + wr * 64) * 16]);
  }
  gload_lds16(pisrc + (lane & 31) * 16, &PiS[wr * 1024]);  // dup in hi 512B
  __syncthreads();

  const char* W2base = (const char*)&W2s[0];
  const char* PjBase = (const char*)&PjS[0];
  const char* PiBase = (const char*)&PiS[0] + wr * 1024 + quad * 16;
  // shared chunk-swizzle base for W2 and Pj ([16 rows x 512B], c = ks*4+quad):
  const int sw16 = l15 * 512 + (((quad ^ l15) & 15) << 4);

  floatx4 acc[2][8];
#pragma unroll
  for (int mt = 0; mt < 2; ++mt)
#pragma unroll
    for (int nt = 0; nt < 8; ++nt) acc[mt][nt] = (floatx4)0.f;

  union U4 { uint4 v; half8 h; };
  U4 piR[2], pjR[2][2];
  piR[0].v = *(const uint4*)(PiBase);
  pjR[0][0].v = *(const uint4*)(PjBase + sw16);
  pjR[0][1].v = *(const uint4*)(PjBase + 8192 + sw16);   // mt=1: +16 rows

  uint4 bfA[4], bfB[4];
  {
    const char* b0 = W2base + sw16;
#pragma unroll
    for (int q = 0; q < 4; ++q) bfA[q] = *(const uint4*)(b0 + q * 8192);
  }

#pragma unroll
  for (int ks = 0; ks < 8; ++ks) {
    const int cur = ks & 1, nxt = cur ^ 1;
    // (1) issue NEXT iteration's B-frag reads (4x b128, paired chans)
    if (ks < 7) {
      const char* bn = W2base + (sw16 ^ ((ks + 1) << 6));
#pragma unroll
      for (int q = 0; q < 4; ++q)
        ((ks & 1) ? bfA : bfB)[q] = *(const uint4*)(bn + q * 8192);
    }
    // (2) depth-1 LDS prefetch of pi/pj for ks+1
    if (ks < 7) {
      piR[nxt].v = *(const uint4*)(PiBase + (ks + 1) * 64);
      const char* pj = PjBase + (sw16 ^ ((ks + 1) << 6));
      pjR[nxt][0].v = *(const uint4*)(pj);
      pjR[nxt][1].v = *(const uint4*)(pj + 8192);
    }
    // (3) build A-frags: packed fp16 relu(Pi+Pj), then pack to e4m3
    const half8 s0 = __builtin_elementwise_max(piR[cur].h + pjR[cur][0].h,
                                               (half8)(_Float16)0);
    const half8 s1 = __builtin_elementwise_max(piR[cur].h + pjR[cur][1].h,
                                               (half8)(_Float16)0);
    const long a0 = pack_fp8(s0);
    const long a1 = pack_fp8(s1);
    // (4) MFMA burst on CURRENT buffer; lo/hi 8B of each b128 = nt 2q / 2q+1
    const uint4* bc = (ks & 1) ? bfB : bfA;
    __builtin_amdgcn_s_setprio(1);
#pragma unroll
    for (int q = 0; q < 4; ++q) {
      const long blo = (long)bc[q].x | ((long)bc[q].y << 32);
      const long bhi = (long)bc[q].z | ((long)bc[q].w << 32);
      acc[0][2 * q]     = __builtin_amdgcn_mfma_f32_16x16x32_fp8_fp8(a0, blo, acc[0][2 * q], 0, 0, 0);
      acc[1][2 * q]     = __builtin_amdgcn_mfma_f32_16x16x32_fp8_fp8(a1, blo, acc[1][2 * q], 0, 0, 0);
      acc[0][2 * q + 1] = __builtin_amdgcn_mfma_f32_16x16x32_fp8_fp8(a0, bhi, acc[0][2 * q + 1], 0, 0, 0);
      acc[1][2 * q + 1] = __builtin_amdgcn_mfma_f32_16x16x32_fp8_fp8(a1, bhi, acc[1][2 * q + 1], 0, 0, 0);
    }
    __builtin_amdgcn_s_setprio(0);
  }

  // epilogue: score[j] = tanh(sum_n W3[n]*relu(C[j,n]/16 + b2[n]) + b3)
  float* orow = outm + ((b << 8) + i) * 256 + jt * 32;
  const float b3v = b3[0];
  const float s16 = 0.0625f;               // undo W2 x16 scale
#pragma unroll
  for (int mt = 0; mt < 2; ++mt) {
    float p0 = 0, p1 = 0, p2 = 0, p3 = 0;
#pragma unroll
    for (int nt = 0; nt < 8; ++nt) {
      float w3v = W3[nt * 16 + l15];
      float b2v = b2[nt * 16 + l15];
      floatx4 a = acc[mt][nt];
      p0 += fmaxf(fmaf(a[0], s16, b2v), 0.f) * w3v;
      p1 += fmaxf(fmaf(a[1], s16, b2v), 0.f) * w3v;
      p2 += fmaxf(fmaf(a[2], s16, b2v), 0.f) * w3v;
      p3 += fmaxf(fmaf(a[3], s16, b2v), 0.f) * w3v;
    }
#pragma unroll
    for (int m = 8; m >= 1; m >>= 1) {   // reduce over the 16 n-cols per quad
      p0 += __shfl_xor(p0, m, 16);
      p1 += __shfl_xor(p1, m, 16);
      p2 += __shfl_xor(p2, m, 16);
      p3 += __shfl_xor(p3, m, 16);
    }
    if (l15 == 0) {
      const int jl = jt * 32 + mt * 16 + quad * 4;   // global j of reg 0
      float ps[4] = {p0, p1, p2, p3};
#pragma unroll
      for (int r = 0; r < 4; ++r) {
        int j = jl + r;
        float sc = fast_tanh(ps[r] + b3v);
        bool valid = (j >= i + 2) && (j - i != 255);
        orow[mt * 16 + quad * 4 + r] = valid ? sc : 0.f;
      }
    }
  }
}

extern "C" void kernel_launch(void* const* d_in, const int* in_sizes, int n_in,
                              void* d_out, int out_size, void* d_ws, size_t ws_size,
                              hipStream_t stream) {
  const float* x  = (const float*)d_in[0];   // [8,256,128]
  const float* W1 = (const float*)d_in[1];   // [512,256]
  const float* b1 = (const float*)d_in[2];   // [256]
  const float* W2 = (const float*)d_in[3];   // [256,128]
  const float* b2 = (const float*)d_in[4];   // [128]
  const float* W3 = (const float*)d_in[5];   // [128]
  const float* b3 = (const float*)d_in[6];   // [1]
  float* out = (float*)d_out;

  // ws (ushort units): PiH 524288 | PjH 524288 | W1T 131072 | xcat 524288 | W2F8 32KB
  unsigned short* PiH  = (unsigned short*)d_ws;
  unsigned short* PjH  = PiH + 524288;
  unsigned short* W1T  = PjH + 524288;
  unsigned short* xcat = W1T + 131072;
  unsigned char*  W2F8 = (unsigned char*)(xcat + 524288);

  k_prep<<<4680, 256, 0, stream>>>(x, W1, W2, out, W2F8, W1T, xcat);
  k_proj<<<256, 256, 0, stream>>>(xcat, W1T, b1, PiH, PjH);
  k_main<<<2304, 256, 0, stream>>>(PiH, PjH, W2F8, b2, W3, b3, out + 2048);
}